// Round 5
// baseline (696.648 us; speedup 1.0000x reference)
//
#include <hip/hip_runtime.h>

#define NN        10000   // nodes
#define D_IN      256     // in channels
#define EE        8192    // target edges
#define GROUPS    157     // u64 words per packed row (ceil(10000/64))
#define ROW_U64   160     // padded packed-row stride in u64
#define UNITS4    312     // full 32-int units per row (312*32 = 9984, tail 16)

typedef unsigned long long u64;

// Encoding probe: adj01 byte offset 10001.
//   byte encoding  -> adj01[1,1] diagonal, guaranteed 1 (adj01 |= eye)
//   int32 encoding -> byte 1 of element 2500 (value 0/1), guaranteed 0
__device__ __forceinline__ bool probe_is_byte(const unsigned char* adj01_bytes) {
    return adj01_bytes[10001] != 0;
}

// ---------------------------------------------------------------------------
// Mark rows that appear as edge endpoints (rowmask pre-zeroed by memsetAsync).
// ---------------------------------------------------------------------------
__global__ void mark_kernel(const int* __restrict__ tar,
                            unsigned char* __restrict__ rowmask) {
    const int i = blockIdx.x * 256 + threadIdx.x;
    if (i < 2 * EE) rowmask[tar[i]] = 1;
}

// ---------------------------------------------------------------------------
// Fused per-node kernel: one WAVE per row (grid 2500 x 256 = 4 rows/block).
//   y1[row] = x[row,:]·W[D:2D],  y2[row] = x[row,:]·W[2D:3D]   (all rows)
//   p1[row,:] = bit-packed adj1 row                           (marked rows)
// Pack: each lane handles 32 elements/iter -> 4 mask bytes, stored as one
// uint (coalesced 256B/wave stores); 8 independent uint4 loads in flight.
// ---------------------------------------------------------------------------
__global__ void node_kernel(const float* __restrict__ x,
                            const float* __restrict__ W,
                            const void* __restrict__ adj1,
                            const unsigned char* __restrict__ adj01_bytes,
                            const unsigned char* __restrict__ rowmask,
                            float* __restrict__ y1,
                            float* __restrict__ y2,
                            u64* __restrict__ p1) {
    const int lane = threadIdx.x & 63, wave = threadIdx.x >> 6;
    const int row = blockIdx.x * 4 + wave;

    // ---- y1/y2: per-wave float4 dot ----
    const float4 xv = ((const float4*)(x + (size_t)row * D_IN))[lane];
    const float4 w1 = ((const float4*)(W + D_IN))[lane];
    const float4 w2 = ((const float4*)(W + 2 * D_IN))[lane];
    float s1 = xv.x * w1.x + xv.y * w1.y + xv.z * w1.z + xv.w * w1.w;
    float s2 = xv.x * w2.x + xv.y * w2.y + xv.z * w2.z + xv.w * w2.w;
    #pragma unroll
    for (int off = 32; off > 0; off >>= 1) {
        s1 += __shfl_down(s1, off);
        s2 += __shfl_down(s2, off);
    }
    if (lane == 0) { y1[row] = s1; y2[row] = s2; }

    if (!rowmask[row]) return;   // wave-uniform: row not used by any edge

    // ---- bit-pack adj1 row ----
    unsigned char* drow = (unsigned char*)(p1 + (size_t)row * ROW_U64);
    unsigned* drow32 = (unsigned*)drow;

    if (!probe_is_byte(adj01_bytes)) {
        // int32 elements: unit = 32 ints = 8 uint4 loads -> one uint mask word
        const uint4* src = (const uint4*)((const int*)adj1 + (size_t)row * NN);
        for (int u = lane; u < UNITS4; u += 64) {
            uint4 q[8];
            #pragma unroll
            for (int k = 0; k < 8; ++k) q[k] = src[u * 8 + k];
            unsigned m = 0;
            #pragma unroll
            for (int k = 0; k < 8; ++k) {
                m |= (q[k].x ? 1u : 0u) << (4 * k + 0);
                m |= (q[k].y ? 1u : 0u) << (4 * k + 1);
                m |= (q[k].z ? 1u : 0u) << (4 * k + 2);
                m |= (q[k].w ? 1u : 0u) << (4 * k + 3);
            }
            drow32[u] = m;
        }
        // tail: ints 9984..9999 -> mask bytes 1248,1249
        if (lane < 2) {
            const int* s32 = (const int*)adj1 + (size_t)row * NN + 9984 + lane * 8;
            unsigned m = 0;
            #pragma unroll
            for (int b = 0; b < 8; ++b) m |= (s32[b] ? 1u : 0u) << b;
            drow[1248 + lane] = (unsigned char)m;
        }
    } else {
        // byte elements: unit = 32 bytes = 2 uint4 loads -> one uint mask word
        const uint4* src = (const uint4*)((const unsigned char*)adj1 + (size_t)row * NN);
        for (int u = lane; u < UNITS4; u += 64) {
            const uint4 a = src[u * 2], b = src[u * 2 + 1];
            unsigned m = 0;
            const unsigned w[8] = { a.x, a.y, a.z, a.w, b.x, b.y, b.z, b.w };
            #pragma unroll
            for (int k = 0; k < 8; ++k) {
                #pragma unroll
                for (int j = 0; j < 4; ++j)
                    m |= (((w[k] >> (8 * j)) & 0xFFu) ? 1u : 0u) << (4 * k + j);
            }
            drow32[u] = m;
        }
        if (lane < 2) {
            const unsigned char* s8 = (const unsigned char*)adj1 + (size_t)row * NN + 9984 + lane * 8;
            unsigned m = 0;
            #pragma unroll
            for (int b = 0; b < 8; ++b) m |= (s8[b] ? 1u : 0u) << b;
            drow[1248 + lane] = (unsigned char)m;
        }
    }
    // pad bytes [1250, 1280)
    if (lane >= 2 && lane < 32) drow[1248 + lane] = 0;
}

// ---------------------------------------------------------------------------
// Per-edge (one block per edge e):
//   out[e] = sum_d x[ti,d]x[tj,d]W[d] + sum_{cn1} y2 + closed-form cn0 + b
//   cn1 = adj1[ti,:] & adj1[tj,:]  (packed-row AND)
//   cn0 (ti!=tj): tj iff a[ti,tj]&&!a[tj,tj];  ti iff a[tj,ti]&&!a[ti,ti]
//   cn0 (ti==tj): ti iff !a[ti,ti]
// ---------------------------------------------------------------------------
__global__ void edge_packed_kernel(const float* __restrict__ x,
                                   const int* __restrict__ tar,
                                   const float* __restrict__ W,
                                   const float* __restrict__ bxs,
                                   const float* __restrict__ y1,
                                   const float* __restrict__ y2,
                                   const u64* __restrict__ p1,
                                   float* __restrict__ out) {
    const int e = blockIdx.x, tid = threadIdx.x;
    const int ti = tar[e], tj = tar[EE + e];

    float acc = x[(size_t)ti * D_IN + tid] * x[(size_t)tj * D_IN + tid] * W[tid];

    if (tid < GROUPS) {
        u64 c1 = p1[(size_t)ti * ROW_U64 + tid] & p1[(size_t)tj * ROW_U64 + tid];
        const int base = tid * 64;
        while (c1) { acc += y2[base + __builtin_ctzll(c1)]; c1 &= c1 - 1; }
    }

    if (tid == 0) {
        #define BIT(r, c) ((int)((p1[(size_t)(r) * ROW_U64 + ((c) >> 6)] >> ((c) & 63)) & 1ull))
        if (ti != tj) {
            if (BIT(ti, tj) && !BIT(tj, tj)) acc += y1[tj];
            if (BIT(tj, ti) && !BIT(ti, ti)) acc += y1[ti];
        } else {
            if (!BIT(ti, ti)) acc += y1[ti];
        }
        #undef BIT
    }

    #pragma unroll
    for (int off = 32; off > 0; off >>= 1) acc += __shfl_down(acc, off);
    __shared__ float part[4];
    const int lane = tid & 63, wid = tid >> 6;
    if (lane == 0) part[wid] = acc;
    __syncthreads();
    if (tid == 0) out[e] = part[0] + part[1] + part[2] + part[3] + bxs[0];
}

// ---------------------------------------------------------------------------
// Fallback (ws too small for bitmap): direct adj1 row scan, same math.
// ---------------------------------------------------------------------------
__global__ void edge_direct_kernel(const float* __restrict__ x,
                                   const void* __restrict__ adj1,
                                   const unsigned char* __restrict__ adj01_bytes,
                                   const int* __restrict__ tar,
                                   const float* __restrict__ W,
                                   const float* __restrict__ bxs,
                                   const float* __restrict__ y1,
                                   const float* __restrict__ y2,
                                   float* __restrict__ out) {
    const int e = blockIdx.x, tid = threadIdx.x;
    const int ti = tar[e], tj = tar[EE + e];
    const bool isByte = probe_is_byte(adj01_bytes);
    float acc = x[(size_t)ti * D_IN + tid] * x[(size_t)tj * D_IN + tid] * W[tid];

    #define AD(r, c) (isByte ? (((const unsigned char*)adj1)[(size_t)(r) * NN + (c)] != 0) \
                             : (((const int*)adj1)[(size_t)(r) * NN + (c)] != 0))
    for (int n = tid; n < NN; n += 256)
        if (AD(ti, n) && AD(tj, n)) acc += y2[n];
    if (tid == 0) {
        if (ti != tj) {
            if (AD(ti, tj) && !AD(tj, tj)) acc += y1[tj];
            if (AD(tj, ti) && !AD(ti, ti)) acc += y1[ti];
        } else if (!AD(ti, ti)) acc += y1[ti];
    }
    #undef AD

    #pragma unroll
    for (int off = 32; off > 0; off >>= 1) acc += __shfl_down(acc, off);
    __shared__ float part[4];
    const int lane = tid & 63, wid = tid >> 6;
    if (lane == 0) part[wid] = acc;
    __syncthreads();
    if (tid == 0) out[e] = part[0] + part[1] + part[2] + part[3] + bxs[0];
}

// ---------------------------------------------------------------------------
extern "C" void kernel_launch(void* const* d_in, const int* in_sizes, int n_in,
                              void* d_out, int out_size, void* d_ws, size_t ws_size,
                              hipStream_t stream) {
    const float*         x     = (const float*)d_in[0];
    const unsigned char* adj01 = (const unsigned char*)d_in[1];  // probe only
    const void*          adj1  = d_in[2];
    const int*           tar   = (const int*)d_in[3];
    const float*         W     = (const float*)d_in[4];
    const float*         bxs   = (const float*)d_in[5];

    // ws layout: [y1:40000B][y2:40000B][rowmask:10000B][pad][p1:12.8MB]
    float*         y1      = (float*)d_ws;
    float*         y2      = y1 + NN;
    unsigned char* rowmask = (unsigned char*)(y2 + NN);
    u64*           p1      = (u64*)((char*)d_ws +
                              ((2 * NN * sizeof(float) + NN + 255) & ~(size_t)255));
    const size_t need = ((2 * NN * sizeof(float) + NN + 255) & ~(size_t)255)
                      + (size_t)NN * ROW_U64 * sizeof(u64);

    float* out = (float*)d_out;

    if (ws_size >= need) {
        hipMemsetAsync(rowmask, 0, NN, stream);
        mark_kernel<<<(2 * EE + 255) / 256, 256, 0, stream>>>(tar, rowmask);
        node_kernel<<<NN / 4, 256, 0, stream>>>(x, W, adj1, adj01, rowmask, y1, y2, p1);
        edge_packed_kernel<<<EE, 256, 0, stream>>>(x, tar, W, bxs, y1, y2, p1, out);
    } else {
        hipMemsetAsync(rowmask, 1, NN, stream);  // pack-all placeholder (p1 unused)
        node_kernel<<<NN / 4, 256, 0, stream>>>(x, W, adj1, adj01, rowmask, y1, y2,
                                                (u64*)y1 /*unused*/);
        edge_direct_kernel<<<EE, 256, 0, stream>>>(x, adj1, adj01, tar, W, bxs, y1, y2, out);
    }
}

// Round 6
// 693.641 us; speedup vs baseline: 1.0043x; 1.0043x over previous
//
#include <hip/hip_runtime.h>

#define NN        10000   // nodes
#define D_IN      256     // in channels
#define EE        8192    // target edges
#define GROUPS    157     // u64 words per packed row (ceil(10000/64))
#define ROW_U64   160     // padded packed-row stride in u64 (1280 B)
#define PACK_T    320     // packing threads per row: units 0..319 (4B mask each)

typedef unsigned long long u64;

// Encoding probe: adj01 byte offset 10001.
//   byte encoding  -> adj01[1,1] diagonal, guaranteed 1 (adj01 |= eye)
//   int32 encoding -> byte 1 of element 2500 (value 0/1), guaranteed 0
__device__ __forceinline__ bool probe_is_byte(const unsigned char* adj01_bytes) {
    return adj01_bytes[10001] != 0;
}

// ---------------------------------------------------------------------------
// Fused streaming kernel: one block (384 thr) per adjacency row.
//   threads 0..319 : pack unit u = tid (32 elements -> one uint mask word)
//                    8 independent uint4 loads, 1 coalesced uint store
//   threads 320..383 (wave 5): y1[row], y2[row] via float4 + wave shuffle
// No LDS, no __syncthreads — every wave fully independent.
// ---------------------------------------------------------------------------
__global__ void pack_y_kernel(const float* __restrict__ x,
                              const float* __restrict__ W,
                              const void* __restrict__ adj1,
                              const unsigned char* __restrict__ adj01_bytes,
                              float* __restrict__ y1,
                              float* __restrict__ y2,
                              u64* __restrict__ p1) {
    const int row = blockIdx.x, tid = threadIdx.x;

    if (tid >= PACK_T) {                       // wave 5: y1/y2 dot products
        const int lane = tid - PACK_T;         // 0..63, lane of this wave
        const float4 xv = ((const float4*)(x + (size_t)row * D_IN))[lane];
        const float4 w1 = ((const float4*)(W + D_IN))[lane];
        const float4 w2 = ((const float4*)(W + 2 * D_IN))[lane];
        float s1 = xv.x * w1.x + xv.y * w1.y + xv.z * w1.z + xv.w * w1.w;
        float s2 = xv.x * w2.x + xv.y * w2.y + xv.z * w2.z + xv.w * w2.w;
        #pragma unroll
        for (int off = 32; off > 0; off >>= 1) {
            s1 += __shfl_down(s1, off);
            s2 += __shfl_down(s2, off);
        }
        if (lane == 0) { y1[row] = s1; y2[row] = s2; }
        return;
    }

    unsigned* drow32 = (unsigned*)(p1 + (size_t)row * ROW_U64);
    const int u = tid;                         // unit index within padded row

    if (u >= 313) { drow32[u] = 0; return; }   // pad units

    unsigned m = 0;
    if (!probe_is_byte(adj01_bytes)) {
        // int32 elements: unit = 32 ints
        const uint4* src = (const uint4*)((const int*)adj1 + (size_t)row * NN) + u * 8;
        if (u < 312) {
            uint4 q[8];
            #pragma unroll
            for (int k = 0; k < 8; ++k) q[k] = src[k];
            #pragma unroll
            for (int k = 0; k < 8; ++k) {
                m |= (q[k].x ? 1u : 0u) << (4 * k + 0);
                m |= (q[k].y ? 1u : 0u) << (4 * k + 1);
                m |= (q[k].z ? 1u : 0u) << (4 * k + 2);
                m |= (q[k].w ? 1u : 0u) << (4 * k + 3);
            }
        } else {                               // u == 312: tail ints 9984..9999
            uint4 q[4];
            #pragma unroll
            for (int k = 0; k < 4; ++k) q[k] = src[k];
            #pragma unroll
            for (int k = 0; k < 4; ++k) {
                m |= (q[k].x ? 1u : 0u) << (4 * k + 0);
                m |= (q[k].y ? 1u : 0u) << (4 * k + 1);
                m |= (q[k].z ? 1u : 0u) << (4 * k + 2);
                m |= (q[k].w ? 1u : 0u) << (4 * k + 3);
            }
        }
    } else {
        // byte elements: unit = 32 bytes
        const uint4* src = (const uint4*)((const unsigned char*)adj1 + (size_t)row * NN) + u * 2;
        if (u < 312) {
            const uint4 a = src[0], b = src[1];
            const unsigned w[8] = { a.x, a.y, a.z, a.w, b.x, b.y, b.z, b.w };
            #pragma unroll
            for (int k = 0; k < 8; ++k)
                #pragma unroll
                for (int j = 0; j < 4; ++j)
                    m |= (((w[k] >> (8 * j)) & 0xFFu) ? 1u : 0u) << (4 * k + j);
        } else {                               // u == 312: tail bytes 9984..9999
            const uint4 a = src[0];
            const unsigned w[4] = { a.x, a.y, a.z, a.w };
            #pragma unroll
            for (int k = 0; k < 4; ++k)
                #pragma unroll
                for (int j = 0; j < 4; ++j)
                    m |= (((w[k] >> (8 * j)) & 0xFFu) ? 1u : 0u) << (4 * k + j);
        }
    }
    drow32[u] = m;
}

// ---------------------------------------------------------------------------
// Per-edge (one block per edge e):
//   out[e] = sum_d x[ti,d]x[tj,d]W[d] + sum_{cn1} y2 + closed-form cn0 + b
//   cn1 = adj1[ti,:] & adj1[tj,:]  (packed-row AND)
//   cn0 (ti!=tj): tj iff a[ti,tj]&&!a[tj,tj];  ti iff a[tj,ti]&&!a[ti,ti]
//   cn0 (ti==tj): ti iff !a[ti,ti]
// ---------------------------------------------------------------------------
__global__ void edge_packed_kernel(const float* __restrict__ x,
                                   const int* __restrict__ tar,
                                   const float* __restrict__ W,
                                   const float* __restrict__ bxs,
                                   const float* __restrict__ y1,
                                   const float* __restrict__ y2,
                                   const u64* __restrict__ p1,
                                   float* __restrict__ out) {
    const int e = blockIdx.x, tid = threadIdx.x;
    const int ti = tar[e], tj = tar[EE + e];

    float acc = x[(size_t)ti * D_IN + tid] * x[(size_t)tj * D_IN + tid] * W[tid];

    if (tid < GROUPS) {
        u64 c1 = p1[(size_t)ti * ROW_U64 + tid] & p1[(size_t)tj * ROW_U64 + tid];
        const int base = tid * 64;
        while (c1) { acc += y2[base + __builtin_ctzll(c1)]; c1 &= c1 - 1; }
    }

    if (tid == 0) {
        #define BIT(r, c) ((int)((p1[(size_t)(r) * ROW_U64 + ((c) >> 6)] >> ((c) & 63)) & 1ull))
        if (ti != tj) {
            if (BIT(ti, tj) && !BIT(tj, tj)) acc += y1[tj];
            if (BIT(tj, ti) && !BIT(ti, ti)) acc += y1[ti];
        } else {
            if (!BIT(ti, ti)) acc += y1[ti];
        }
        #undef BIT
    }

    #pragma unroll
    for (int off = 32; off > 0; off >>= 1) acc += __shfl_down(acc, off);
    __shared__ float part[4];
    const int lane = tid & 63, wid = tid >> 6;
    if (lane == 0) part[wid] = acc;
    __syncthreads();
    if (tid == 0) out[e] = part[0] + part[1] + part[2] + part[3] + bxs[0];
}

// ---------------------------------------------------------------------------
// Fallback (ws too small for bitmap): direct adj1 row scan, same math.
// ---------------------------------------------------------------------------
__global__ void edge_direct_kernel(const float* __restrict__ x,
                                   const void* __restrict__ adj1,
                                   const unsigned char* __restrict__ adj01_bytes,
                                   const int* __restrict__ tar,
                                   const float* __restrict__ W,
                                   const float* __restrict__ bxs,
                                   const float* __restrict__ y1,
                                   const float* __restrict__ y2,
                                   float* __restrict__ out) {
    const int e = blockIdx.x, tid = threadIdx.x;
    const int ti = tar[e], tj = tar[EE + e];
    const bool isByte = probe_is_byte(adj01_bytes);
    float acc = x[(size_t)ti * D_IN + tid] * x[(size_t)tj * D_IN + tid] * W[tid];

    #define AD(r, c) (isByte ? (((const unsigned char*)adj1)[(size_t)(r) * NN + (c)] != 0) \
                             : (((const int*)adj1)[(size_t)(r) * NN + (c)] != 0))
    for (int n = tid; n < NN; n += 256)
        if (AD(ti, n) && AD(tj, n)) acc += y2[n];
    if (tid == 0) {
        if (ti != tj) {
            if (AD(ti, tj) && !AD(tj, tj)) acc += y1[tj];
            if (AD(tj, ti) && !AD(ti, ti)) acc += y1[ti];
        } else if (!AD(ti, ti)) acc += y1[ti];
    }
    #undef AD

    #pragma unroll
    for (int off = 32; off > 0; off >>= 1) acc += __shfl_down(acc, off);
    __shared__ float part[4];
    const int lane = tid & 63, wid = tid >> 6;
    if (lane == 0) part[wid] = acc;
    __syncthreads();
    if (tid == 0) out[e] = part[0] + part[1] + part[2] + part[3] + bxs[0];
}

// ---------------------------------------------------------------------------
// Fallback y1/y2 (only used with edge_direct path).
// ---------------------------------------------------------------------------
__global__ void y_only_kernel(const float* __restrict__ x,
                              const float* __restrict__ W,
                              float* __restrict__ y1,
                              float* __restrict__ y2) {
    const int lane = threadIdx.x & 63, wave = threadIdx.x >> 6;
    const int row = blockIdx.x * 4 + wave;
    const float4 xv = ((const float4*)(x + (size_t)row * D_IN))[lane];
    const float4 w1 = ((const float4*)(W + D_IN))[lane];
    const float4 w2 = ((const float4*)(W + 2 * D_IN))[lane];
    float s1 = xv.x * w1.x + xv.y * w1.y + xv.z * w1.z + xv.w * w1.w;
    float s2 = xv.x * w2.x + xv.y * w2.y + xv.z * w2.z + xv.w * w2.w;
    #pragma unroll
    for (int off = 32; off > 0; off >>= 1) {
        s1 += __shfl_down(s1, off);
        s2 += __shfl_down(s2, off);
    }
    if (lane == 0) { y1[row] = s1; y2[row] = s2; }
}

// ---------------------------------------------------------------------------
extern "C" void kernel_launch(void* const* d_in, const int* in_sizes, int n_in,
                              void* d_out, int out_size, void* d_ws, size_t ws_size,
                              hipStream_t stream) {
    const float*         x     = (const float*)d_in[0];
    const unsigned char* adj01 = (const unsigned char*)d_in[1];  // probe only
    const void*          adj1  = d_in[2];
    const int*           tar   = (const int*)d_in[3];
    const float*         W     = (const float*)d_in[4];
    const float*         bxs   = (const float*)d_in[5];

    // ws layout: [y1:40000B][y2:40000B][pad][p1:12.8MB]
    float* y1 = (float*)d_ws;
    float* y2 = y1 + NN;
    u64*   p1 = (u64*)((char*)d_ws + ((2 * NN * sizeof(float) + 255) & ~(size_t)255));
    const size_t need = ((2 * NN * sizeof(float) + 255) & ~(size_t)255)
                      + (size_t)NN * ROW_U64 * sizeof(u64);

    float* out = (float*)d_out;

    if (ws_size >= need) {
        pack_y_kernel<<<NN, 384, 0, stream>>>(x, W, adj1, adj01, y1, y2, p1);
        edge_packed_kernel<<<EE, 256, 0, stream>>>(x, tar, W, bxs, y1, y2, p1, out);
    } else {
        y_only_kernel<<<NN / 4, 256, 0, stream>>>(x, W, y1, y2);
        edge_direct_kernel<<<EE, 256, 0, stream>>>(x, adj1, adj01, tar, W, bxs, y1, y2, out);
    }
}